// Round 3
// baseline (65595.728 us; speedup 1.0000x reference)
//
#include <hip/hip_runtime.h>
#include <cstdint>
#include <cstddef>

// Problem constants
constexpr int Bc = 8, Lc = 4096, DIMc = 384;
constexpr int DSTATEc = 16, DCONVc = 4;
constexpr int DINNERc = 768, DTRANKc = 24, HIDc = 768;
constexpr float EPSc = 1e-5f;

// ---------------------------------------------------------------------------
// x + pos_emb -> fp32 residual stream.  x pre-offset to chunk start (batch
// boundary), so i % (L*DIM) indexes pos correctly.
__global__ __launch_bounds__(256)
void add_pos_k(const float* __restrict__ x, const float* __restrict__ pos,
               float* __restrict__ xres, int nElem) {
    int i = blockIdx.x * 256 + threadIdx.x;
    if (i >= nElem) return;
    int pi = i % (Lc * DIMc);
    xres[i] = x[i] + pos[pi];
}

// ---------------------------------------------------------------------------
// LayerNorm over DIM=384, one wave (64 threads) per token
__global__ __launch_bounds__(64)
void ln_k(const float* __restrict__ X, const float* __restrict__ s, const float* __restrict__ bb,
          float* __restrict__ Y) {
    int token = blockIdx.x;
    int tid = threadIdx.x;
    const float* xr = X + (size_t)token * DIMc;
    float v[6];
    float sum = 0.f;
#pragma unroll
    for (int j = 0; j < 6; j++) { v[j] = xr[tid + j * 64]; sum += v[j]; }
#pragma unroll
    for (int off = 32; off > 0; off >>= 1) sum += __shfl_xor(sum, off);
    float mean = sum * (1.f / DIMc);
    float var = 0.f;
#pragma unroll
    for (int j = 0; j < 6; j++) { float d = v[j] - mean; var += d * d; }
#pragma unroll
    for (int off = 32; off > 0; off >>= 1) var += __shfl_xor(var, off);
    var *= (1.f / DIMc);
    float r = rsqrtf(var + EPSc);
    float* yr = Y + (size_t)token * DIMc;
#pragma unroll
    for (int j = 0; j < 6; j++) {
        int c = tid + j * 64;
        yr[c] = (v[j] - mean) * r * s[c] + bb[c];
    }
}

// ---------------------------------------------------------------------------
// Generic row-major GEMM: Y[token,e] = act( sum_k X[token,k]*W[e,k] + bias[e] )
// Block handles TM=8 tokens; X rows staged in LDS; thread = one e.
// ACT: 0 none, 1 tanh-gelu.  ADD_RESID: accumulate into Yacc.
template<int K, int ACT, bool HAS_BIAS, bool ADD_RESID>
__global__ __launch_bounds__(256)
void gemm_k(const float* __restrict__ X, int ldx, const float* __restrict__ W,
            const float* __restrict__ bias, float* Yb, float* Yacc, int ldy, int E) {
    constexpr int TM = 8;
    __shared__ float xs[TM][K];
    const int m0 = blockIdx.x * TM;
    const int tid = threadIdx.x;
    for (int idx = tid; idx < TM * K; idx += 256) {
        int m = idx / K, k = idx - m * K;
        xs[m][k] = X[(size_t)(m0 + m) * ldx + k];
    }
    __syncthreads();
    for (int e0 = 0; e0 < E; e0 += 256) {
        int e = e0 + tid;
        if (e >= E) break;
        float acc[TM];
#pragma unroll
        for (int m = 0; m < TM; m++) acc[m] = 0.f;
        const float* wrow = W + (size_t)e * K;
        for (int k = 0; k < K; k += 8) {
            float4 w0 = *reinterpret_cast<const float4*>(wrow + k);
            float4 w1 = *reinterpret_cast<const float4*>(wrow + k + 4);
            float wf[8] = {w0.x, w0.y, w0.z, w0.w, w1.x, w1.y, w1.z, w1.w};
#pragma unroll
            for (int j = 0; j < 8; j++)
#pragma unroll
                for (int m = 0; m < TM; m++)
                    acc[m] += xs[m][k + j] * wf[j];
        }
        float bv = HAS_BIAS ? bias[e] : 0.f;
#pragma unroll
        for (int m = 0; m < TM; m++) {
            float v = acc[m] + bv;
            if (ACT == 1) {
                float c = v + 0.044715f * v * v * v;
                float th = tanhf(0.7978845608028654f * c);
                v = 0.5f * v * (1.f + th);
            }
            size_t oi = (size_t)(m0 + m) * ldy + e;
            if (ADD_RESID) Yacc[oi] += v;
            else           Yb[oi] = v;
        }
    }
}

// ---------------------------------------------------------------------------
// Depthwise causal conv (DCONV=4) + SiLU.  xi in xz buffer (ld=1536), out (ld=768).
__global__ __launch_bounds__(256)
void conv_k(const float* __restrict__ xz, const float* __restrict__ cw, const float* __restrict__ cb,
            float* __restrict__ u, int nElem) {
    int i = blockIdx.x * 256 + threadIdx.x;
    if (i >= nElem) return;
    int d = i % DINNERc;
    int token = i / DINNERc;
    int t = token % Lc;
    float acc = cb[d];
#pragma unroll
    for (int k = 0; k < DCONVc; k++) {
        int tt = t + k - (DCONVc - 1);
        if (tt >= 0)
            acc += xz[(size_t)(token + k - (DCONVc - 1)) * (2 * DINNERc) + d] * cw[d * DCONVc + k];
    }
    u[i] = acc / (1.f + expf(-acc));   // silu
}

// ---------------------------------------------------------------------------
// dt = softplus( dbl[:, :24] @ dtproj_w^T + dtproj_b ); output ld=1536
// (written into the dead xi half of the xz buffer).
__global__ __launch_bounds__(256)
void dtproj_k(const float* __restrict__ dbl, const float* __restrict__ dtw,
              const float* __restrict__ dtb, float* __restrict__ out, int nElem) {
    int i = blockIdx.x * 256 + threadIdx.x;
    if (i >= nElem) return;
    int d = i % DINNERc;
    int token = i / DINNERc;
    const float* row = dbl + (size_t)token * 56;
    const float* wr = dtw + (size_t)d * DTRANKc;
    float acc = dtb[d];
#pragma unroll
    for (int r = 0; r < DTRANKc; r++) acc += row[r] * wr[r];
    float sp = fmaxf(acc, 0.f) + log1pf(expf(-fabsf(acc)));   // stable softplus
    out[(size_t)token * (2 * DINNERc) + d] = sp;
}

// ---------------------------------------------------------------------------
// Selective scan.  Thread = (b, d, s); 16 lanes (s) per channel reduce via shfl.
// dt in xz xi-half (ld 1536), z in xz z-half (ld 1536).  y written IN-PLACE
// over u (same buffer; read-before-write within the same wave) -> no restrict.
__global__ __launch_bounds__(256)
void scan_k(const float* dtb, const float* ub,
            const float* __restrict__ dblb, const float* __restrict__ zb,
            const float* __restrict__ A_log, const float* __restrict__ Dp,
            float* yb) {
    int g = blockIdx.x * 256 + threadIdx.x;
    int s = g & 15;
    int d = (g >> 4) % DINNERc;
    int b = g / (DINNERc * DSTATEc);
    float a = -expf(A_log[d * DSTATEc + s]);
    float Dv = Dp[d];
    float h = 0.f;
    size_t base = (size_t)b * Lc;
    for (int t = 0; t < Lc; t++) {
        size_t row = base + t;
        size_t idx = row * DINNERc + d;
        float dt = dtb[row * (2 * DINNERc) + d];
        float uv = ub[idx];
        float Bv = dblb[row * 56 + DTRANKc + s];
        float Cv = dblb[row * 56 + DTRANKc + DSTATEc + s];
        h = h * __expf(dt * a) + dt * uv * Bv;
        float yp = h * Cv;
        yp += __shfl_xor(yp, 1);
        yp += __shfl_xor(yp, 2);
        yp += __shfl_xor(yp, 4);
        yp += __shfl_xor(yp, 8);
        if (s == 0) {
            float zv = zb[row * (2 * DINNERc) + DINNERc + d];
            yb[idx] = (yp + uv * Dv) * (zv / (1.f + __expf(-zv)));
        }
    }
}

// ---------------------------------------------------------------------------
extern "C" void kernel_launch(void* const* d_in, const int* in_sizes, int n_in,
                              void* d_out, int out_size, void* d_ws, size_t ws_size,
                              hipStream_t stream) {
    const float* x        = (const float*)d_in[0];
    const float* pos      = (const float*)d_in[1];
    const float* ln1_s    = (const float*)d_in[2];
    const float* ln1_b    = (const float*)d_in[3];
    const float* in_w     = (const float*)d_in[4];
    const float* conv_w   = (const float*)d_in[5];
    const float* conv_b   = (const float*)d_in[6];
    const float* xproj_w  = (const float*)d_in[7];
    const float* dtproj_w = (const float*)d_in[8];
    const float* dtproj_b = (const float*)d_in[9];
    const float* A_log    = (const float*)d_in[10];
    const float* Dp       = (const float*)d_in[11];
    const float* out_w    = (const float*)d_in[12];
    const float* ff_ln_s  = (const float*)d_in[13];
    const float* ff_ln_b  = (const float*)d_in[14];
    const float* ff_w1    = (const float*)d_in[15];
    const float* ff_b1    = (const float*)d_in[16];
    const float* ff_w2    = (const float*)d_in[17];
    const float* ff_b2    = (const float*)d_in[18];
    const float* lno_s    = (const float*)d_in[19];
    const float* lno_b    = (const float*)d_in[20];
    float* out            = (float*)d_out;

    // Per-batch-element scratch (bytes), all fp32:
    //   xres: 4096*384*4  = 6,291,456
    //   xz:   4096*1536*4 = 25,165,824   (xi half reused for dt)
    //   u:    4096*768*4  = 12,582,912   (y written in-place)
    const size_t perB = 44040192;
    int cb = (int)(ws_size / perB);
    if (cb < 1) cb = 1;
    if (cb > Bc) cb = Bc;

    for (int b0 = 0; b0 < Bc; b0 += cb) {
        int cbc = (Bc - b0 < cb) ? (Bc - b0) : cb;
        int nTok = cbc * Lc;

        char* ws = (char*)d_ws;
        float* xres = (float*)ws;                                        // nTok*384
        float* XZ = (float*)(ws + (size_t)nTok * DIMc * 4);              // nTok*1536
        float* U  = (float*)(ws + (size_t)nTok * DIMc * 4 + (size_t)nTok * 2 * DINNERc * 4); // nTok*768
        // LN-out (T4) and dbl (DBL) live in this chunk's slice of d_out:
        // their lifetimes never overlap each other or the final store.
        float* T4  = out + (size_t)b0 * Lc * DIMc;
        float* DBL = T4;

        add_pos_k<<<(nTok * DIMc + 255) / 256, 256, 0, stream>>>(
            x + (size_t)b0 * Lc * DIMc, pos, xres, nTok * DIMc);

        for (int i = 0; i < 6; i++) {
            ln_k<<<nTok, 64, 0, stream>>>(xres, ln1_s + i * DIMc, ln1_b + i * DIMc, T4);
            gemm_k<384, 0, false, false><<<nTok / 8, 256, 0, stream>>>(
                T4, DIMc, in_w + (size_t)i * 2 * DINNERc * DIMc, nullptr, XZ, nullptr,
                2 * DINNERc, 2 * DINNERc);
            conv_k<<<(nTok * DINNERc + 255) / 256, 256, 0, stream>>>(
                XZ, conv_w + (size_t)i * DINNERc * DCONVc, conv_b + (size_t)i * DINNERc,
                U, nTok * DINNERc);
            gemm_k<768, 0, false, false><<<nTok / 8, 256, 0, stream>>>(
                U, DINNERc, xproj_w + (size_t)i * 56 * DINNERc, nullptr, DBL, nullptr, 56, 56);
            dtproj_k<<<(nTok * DINNERc + 255) / 256, 256, 0, stream>>>(
                DBL, dtproj_w + (size_t)i * DINNERc * DTRANKc, dtproj_b + (size_t)i * DINNERc,
                XZ, nTok * DINNERc);
            scan_k<<<cbc * DINNERc * DSTATEc / 256, 256, 0, stream>>>(
                XZ, U, DBL, XZ, A_log + (size_t)i * DINNERc * DSTATEc,
                Dp + (size_t)i * DINNERc, U);
            gemm_k<768, 0, false, true><<<nTok / 8, 256, 0, stream>>>(
                U, DINNERc, out_w + (size_t)i * DIMc * DINNERc, nullptr, nullptr, xres,
                DIMc, DIMc);
            ln_k<<<nTok, 64, 0, stream>>>(xres, ff_ln_s + i * DIMc, ff_ln_b + i * DIMc, T4);
            gemm_k<384, 1, true, false><<<nTok / 8, 256, 0, stream>>>(
                T4, DIMc, ff_w1 + (size_t)i * HIDc * DIMc, ff_b1 + (size_t)i * HIDc,
                XZ, nullptr, HIDc, HIDc);
            gemm_k<768, 0, true, true><<<nTok / 8, 256, 0, stream>>>(
                XZ, HIDc, ff_w2 + (size_t)i * DIMc * HIDc, ff_b2 + (size_t)i * DIMc,
                nullptr, xres, DIMc, DIMc);
        }

        ln_k<<<nTok, 64, 0, stream>>>(xres, lno_s, lno_b, out + (size_t)b0 * Lc * DIMc);
    }
}

// Round 4
// 53695.605 us; speedup vs baseline: 1.2216x; 1.2216x over previous
//
#include <hip/hip_runtime.h>
#include <cstdint>
#include <cstddef>

// Problem constants
constexpr int Bc = 8, Lc = 4096, DIMc = 384;
constexpr int DSTATEc = 16, DCONVc = 4;
constexpr int DINNERc = 768, DTRANKc = 24, HIDc = 768;
constexpr float EPSc = 1e-5f;
// Scan chunking
constexpr int NCc = 16, TCc = Lc / NCc;   // 16 chunks of 256 steps

// ---------------------------------------------------------------------------
__global__ __launch_bounds__(256)
void add_pos_k(const float* __restrict__ x, const float* __restrict__ pos,
               float* __restrict__ xres, int nElem) {
    int i = blockIdx.x * 256 + threadIdx.x;
    if (i >= nElem) return;
    int pi = i % (Lc * DIMc);
    xres[i] = x[i] + pos[pi];
}

// ---------------------------------------------------------------------------
// LayerNorm over DIM=384, one wave per token.  Safe in-place (X==Y): every
// store transitively depends on all loads (through r).
__global__ __launch_bounds__(64)
void ln_k(const float* __restrict__ X, const float* __restrict__ s, const float* __restrict__ bb,
          float* __restrict__ Y) {
    int token = blockIdx.x;
    int tid = threadIdx.x;
    const float* xr = X + (size_t)token * DIMc;
    float v[6];
    float sum = 0.f;
#pragma unroll
    for (int j = 0; j < 6; j++) { v[j] = xr[tid + j * 64]; sum += v[j]; }
#pragma unroll
    for (int off = 32; off > 0; off >>= 1) sum += __shfl_xor(sum, off);
    float mean = sum * (1.f / DIMc);
    float var = 0.f;
#pragma unroll
    for (int j = 0; j < 6; j++) { float d = v[j] - mean; var += d * d; }
#pragma unroll
    for (int off = 32; off > 0; off >>= 1) var += __shfl_xor(var, off);
    var *= (1.f / DIMc);
    float r = rsqrtf(var + EPSc);
    float* yr = Y + (size_t)token * DIMc;
#pragma unroll
    for (int j = 0; j < 6; j++) {
        int c = tid + j * 64;
        yr[c] = (v[j] - mean) * r * s[c] + bb[c];
    }
}

// ---------------------------------------------------------------------------
// Register-blocked GEMM.  Y[m,e] = act(sum_k X[m,k] W[e,k] + bias).
// ldx == K for all uses.  Block: TG groups of GT=256/TG threads; group g
// handles tokens [m0+g*8, +8); thread handles TE consecutive e columns.
// GT*TE == E exactly.  xs reads are wave-uniform (broadcast, conflict-free).
template<int K, int E, int TE, int TG, int ACT, bool HAS_BIAS, bool ADD_RESID>
__global__ __launch_bounds__(256)
void gemm_big(const float* __restrict__ X, const float* __restrict__ W,
              const float* __restrict__ bias, float* __restrict__ Y, int ldy) {
    constexpr int GT = 256 / TG;
    constexpr int TM = 8 * TG;
    static_assert(GT * TE == E, "config must tile E exactly");
    __shared__ float xs[TM][K];
    const int m0 = blockIdx.x * TM;
    const int tid = threadIdx.x;
    for (int idx = tid; idx < TM * K; idx += 256) {
        int m = idx / K, k = idx - m * K;
        xs[m][k] = X[(size_t)(m0 + m) * K + k];
    }
    __syncthreads();
    const int mg = tid / GT;
    const int eb = (tid % GT) * TE;
    const float* wp[TE];
#pragma unroll
    for (int q = 0; q < TE; q++) wp[q] = W + (size_t)(eb + q) * K;
    float acc[8][TE];
#pragma unroll
    for (int m = 0; m < 8; m++)
#pragma unroll
        for (int q = 0; q < TE; q++) acc[m][q] = 0.f;
    for (int k = 0; k < K; k += 4) {
        float4 xv[8];
#pragma unroll
        for (int m = 0; m < 8; m++)
            xv[m] = *reinterpret_cast<const float4*>(&xs[mg * 8 + m][k]);
        float4 wv[TE];
#pragma unroll
        for (int q = 0; q < TE; q++)
            wv[q] = *reinterpret_cast<const float4*>(wp[q] + k);
#pragma unroll
        for (int q = 0; q < TE; q++)
#pragma unroll
            for (int m = 0; m < 8; m++) {
                acc[m][q] += xv[m].x * wv[q].x;
                acc[m][q] += xv[m].y * wv[q].y;
                acc[m][q] += xv[m].z * wv[q].z;
                acc[m][q] += xv[m].w * wv[q].w;
            }
    }
#pragma unroll
    for (int m = 0; m < 8; m++) {
        int row = m0 + mg * 8 + m;
#pragma unroll
        for (int q = 0; q < TE; q++) {
            float v = acc[m][q] + (HAS_BIAS ? bias[eb + q] : 0.f);
            if (ACT == 1) {
                float c = v + 0.044715f * v * v * v;
                float th = tanhf(0.7978845608028654f * c);
                v = 0.5f * v * (1.f + th);
            }
            size_t oi = (size_t)row * ldy + eb + q;
            if (ADD_RESID) Y[oi] += v;
            else           Y[oi] = v;
        }
    }
}

// ---------------------------------------------------------------------------
// xproj (E=56, K=768): 4 tokens/block, one wave per token, lane = e (<56).
__global__ __launch_bounds__(256)
void xproj_k(const float* __restrict__ X, const float* __restrict__ W,
             float* __restrict__ DBL) {
    __shared__ float xs[4][768];
    int m0 = blockIdx.x * 4;
    int tid = threadIdx.x;
    for (int idx = tid; idx < 4 * 768; idx += 256) {
        int m = idx / 768, k = idx - m * 768;
        xs[m][k] = X[(size_t)(m0 + m) * 768 + k];
    }
    __syncthreads();
    int m = tid >> 6;
    int e = tid & 63;
    if (e < 56) {
        const float* wr = W + (size_t)e * 768;
        float acc = 0.f;
        for (int k = 0; k < 768; k += 4) {
            float4 xv = *reinterpret_cast<const float4*>(&xs[m][k]);
            float4 wv = *reinterpret_cast<const float4*>(wr + k);
            acc += xv.x * wv.x + xv.y * wv.y + xv.z * wv.z + xv.w * wv.w;
        }
        DBL[(size_t)(m0 + m) * 56 + e] = acc;
    }
}

// ---------------------------------------------------------------------------
__global__ __launch_bounds__(256)
void conv_k(const float* __restrict__ xz, const float* __restrict__ cw, const float* __restrict__ cb,
            float* __restrict__ u, int nElem) {
    int i = blockIdx.x * 256 + threadIdx.x;
    if (i >= nElem) return;
    int d = i % DINNERc;
    int token = i / DINNERc;
    int t = token % Lc;
    float acc = cb[d];
#pragma unroll
    for (int k = 0; k < DCONVc; k++) {
        int tt = t + k - (DCONVc - 1);
        if (tt >= 0)
            acc += xz[(size_t)(token + k - (DCONVc - 1)) * (2 * DINNERc) + d] * cw[d * DCONVc + k];
    }
    u[i] = acc / (1.f + expf(-acc));   // silu
}

// ---------------------------------------------------------------------------
__global__ __launch_bounds__(256)
void dtproj_k(const float* __restrict__ dbl, const float* __restrict__ dtw,
              const float* __restrict__ dtb, float* __restrict__ out, int nElem) {
    int i = blockIdx.x * 256 + threadIdx.x;
    if (i >= nElem) return;
    int d = i % DINNERc;
    int token = i / DINNERc;
    const float* row = dbl + (size_t)token * 56;
    const float* wr = dtw + (size_t)d * DTRANKc;
    float acc = dtb[d];
#pragma unroll
    for (int r = 0; r < DTRANKc; r++) acc += row[r] * wr[r];
    float sp = fmaxf(acc, 0.f) + log1pf(expf(-fabsf(acc)));
    out[(size_t)token * (2 * DINNERc) + d] = sp;
}

// ---------------------------------------------------------------------------
// Scan pass 1: per (b,d,s,chunk) compute P = prod(dA) and local h (h0=0).
// Mapping: s = g&15, c = (g>>4)&15, d = (g>>8)%768, b = g/(768*256).
__global__ __launch_bounds__(256)
void scan1_k(const float* __restrict__ dtb, const float* __restrict__ ub,
             const float* __restrict__ dblb, const float* __restrict__ A_log,
             float* __restrict__ Pb, float* __restrict__ Hb) {
    int g = blockIdx.x * 256 + threadIdx.x;
    int s = g & 15;
    int c = (g >> 4) & (NCc - 1);
    int d = (g >> 8) % DINNERc;
    int b = g / (DINNERc * DSTATEc * NCc);
    float a = -expf(A_log[d * DSTATEc + s]);
    size_t row0 = (size_t)b * Lc + c * TCc;
    const float* dtp = dtb + row0 * (2 * DINNERc) + d;
    const float* up  = ub  + row0 * DINNERc + d;
    const float* Bp  = dblb + row0 * 56 + DTRANKc + s;
    float h = 0.f, P = 1.f;
    for (int t = 0; t < TCc; t++) {
        float dt = *dtp, uv = *up, Bv = *Bp;
        float dA = __expf(dt * a);
        h = h * dA + dt * uv * Bv;
        P *= dA;
        dtp += 2 * DINNERc; up += DINNERc; Bp += 56;
    }
    size_t sidx = (((size_t)b * DINNERc + d) * DSTATEc + s) * NCc + c;
    Pb[sidx] = P;
    Hb[sidx] = h;
}

// Scan pass 2: sequential combine over NC chunks per (b,d,s).
__global__ __launch_bounds__(256)
void scan2_k(const float* __restrict__ Pb, const float* __restrict__ Hb,
             float* __restrict__ H0b, int nSeq) {
    int j = blockIdx.x * 256 + threadIdx.x;
    if (j >= nSeq) return;
    size_t base = (size_t)j * NCc;
    float h0 = 0.f;
#pragma unroll
    for (int c = 0; c < NCc; c++) {
        H0b[base + c] = h0;
        h0 = h0 * Pb[base + c] + Hb[base + c];
    }
}

// Scan pass 3: re-run chunk from h0, reduce over s (16-lane shfl), gate, store.
// yb == ub (in-place; lanes read u before lane 0 writes y, same wave).
__global__ __launch_bounds__(256)
void scan3_k(const float* __restrict__ dtb, const float* ub,
             const float* __restrict__ dblb, const float* __restrict__ zb,
             const float* __restrict__ A_log, const float* __restrict__ Dp,
             const float* __restrict__ H0b, float* yb) {
    int g = blockIdx.x * 256 + threadIdx.x;
    int s = g & 15;
    int c = (g >> 4) & (NCc - 1);
    int d = (g >> 8) % DINNERc;
    int b = g / (DINNERc * DSTATEc * NCc);
    float a = -expf(A_log[d * DSTATEc + s]);
    float Dv = Dp[d];
    size_t sidx = (((size_t)b * DINNERc + d) * DSTATEc + s) * NCc + c;
    float h = H0b[sidx];
    size_t row0 = (size_t)b * Lc + c * TCc;
    const float* dtp = dtb + row0 * (2 * DINNERc) + d;
    const float* up  = ub  + row0 * DINNERc + d;
    const float* Bp  = dblb + row0 * 56 + DTRANKc + s;
    const float* Cp  = dblb + row0 * 56 + DTRANKc + DSTATEc + s;
    const float* zp  = zb + row0 * (2 * DINNERc) + DINNERc + d;
    float* yp = yb + row0 * DINNERc + d;
    for (int t = 0; t < TCc; t++) {
        float dt = *dtp, uv = *up, Bv = *Bp, Cv = *Cp;
        float dA = __expf(dt * a);
        h = h * dA + dt * uv * Bv;
        float y = h * Cv;
        y += __shfl_xor(y, 1);
        y += __shfl_xor(y, 2);
        y += __shfl_xor(y, 4);
        y += __shfl_xor(y, 8);
        if (s == 0) {
            float zv = *zp;
            *yp = (y + uv * Dv) * (zv / (1.f + __expf(-zv)));
        }
        dtp += 2 * DINNERc; up += DINNERc; Bp += 56; Cp += 56;
        zp += 2 * DINNERc; yp += DINNERc;
    }
}

// ---------------------------------------------------------------------------
extern "C" void kernel_launch(void* const* d_in, const int* in_sizes, int n_in,
                              void* d_out, int out_size, void* d_ws, size_t ws_size,
                              hipStream_t stream) {
    const float* x        = (const float*)d_in[0];
    const float* pos      = (const float*)d_in[1];
    const float* ln1_s    = (const float*)d_in[2];
    const float* ln1_b    = (const float*)d_in[3];
    const float* in_w     = (const float*)d_in[4];
    const float* conv_w   = (const float*)d_in[5];
    const float* conv_b   = (const float*)d_in[6];
    const float* xproj_w  = (const float*)d_in[7];
    const float* dtproj_w = (const float*)d_in[8];
    const float* dtproj_b = (const float*)d_in[9];
    const float* A_log    = (const float*)d_in[10];
    const float* Dp       = (const float*)d_in[11];
    const float* out_w    = (const float*)d_in[12];
    const float* ff_ln_s  = (const float*)d_in[13];
    const float* ff_ln_b  = (const float*)d_in[14];
    const float* ff_w1    = (const float*)d_in[15];
    const float* ff_b1    = (const float*)d_in[16];
    const float* ff_w2    = (const float*)d_in[17];
    const float* ff_b2    = (const float*)d_in[18];
    const float* lno_s    = (const float*)d_in[19];
    const float* lno_b    = (const float*)d_in[20];
    float* out            = (float*)d_out;

    // Residual stream lives in d_out (fp32, full size).
    float* xres = out;

    // Per-batch ws need: XZ 25165824 + U 12582912 + T4 6291456 + scan 2359296
    const size_t perB = (size_t)Lc * 2 * DINNERc * 4 + (size_t)Lc * DINNERc * 4
                      + (size_t)Lc * DIMc * 4 + 3ull * DINNERc * DSTATEc * NCc * 4;
    int cb = (int)(ws_size / perB);
    if (cb < 1) cb = 1;
    if (cb > Bc) cb = Bc;

    char* p = (char*)d_ws;
    float* XZ = (float*)p;  p += (size_t)cb * Lc * 2 * DINNERc * 4;
    float* U  = (float*)p;  p += (size_t)cb * Lc * DINNERc * 4;
    float* T4 = (float*)p;  p += (size_t)cb * Lc * DIMc * 4;     // also hosts DBL (ld 56)
    float* SP = (float*)p;  p += (size_t)cb * DINNERc * DSTATEc * NCc * 4;
    float* SH = (float*)p;  p += (size_t)cb * DINNERc * DSTATEc * NCc * 4;
    float* SH0 = (float*)p;
    float* DBL = T4;

    add_pos_k<<<(Bc * Lc * DIMc + 255) / 256, 256, 0, stream>>>(
        x, pos, xres, Bc * Lc * DIMc);

    for (int b0 = 0; b0 < Bc; b0 += cb) {
        int cbc = (Bc - b0 < cb) ? (Bc - b0) : cb;
        int nTok = cbc * Lc;
        float* xrs = xres + (size_t)b0 * Lc * DIMc;

        for (int i = 0; i < 6; i++) {
            ln_k<<<nTok, 64, 0, stream>>>(xrs, ln1_s + i * DIMc, ln1_b + i * DIMc, T4);
            gemm_big<384, 1536, 6, 1, 0, false, false><<<nTok / 8, 256, 0, stream>>>(
                T4, in_w + (size_t)i * 2 * DINNERc * DIMc, nullptr, XZ, 1536);
            conv_k<<<nTok * DINNERc / 256, 256, 0, stream>>>(
                XZ, conv_w + (size_t)i * DINNERc * DCONVc, conv_b + (size_t)i * DINNERc,
                U, nTok * DINNERc);
            xproj_k<<<nTok / 4, 256, 0, stream>>>(
                U, xproj_w + (size_t)i * 56 * DINNERc, DBL);
            dtproj_k<<<nTok * DINNERc / 256, 256, 0, stream>>>(
                DBL, dtproj_w + (size_t)i * DINNERc * DTRANKc, dtproj_b + (size_t)i * DINNERc,
                XZ, nTok * DINNERc);
            scan1_k<<<cbc * DINNERc, 256, 0, stream>>>(
                XZ, U, DBL, A_log + (size_t)i * DINNERc * DSTATEc, SP, SH);
            scan2_k<<<(cbc * DINNERc * DSTATEc + 255) / 256, 256, 0, stream>>>(
                SP, SH, SH0, cbc * DINNERc * DSTATEc);
            scan3_k<<<cbc * DINNERc, 256, 0, stream>>>(
                XZ, U, DBL, XZ, A_log + (size_t)i * DINNERc * DSTATEc,
                Dp + (size_t)i * DINNERc, SH0, U);
            gemm_big<768, 384, 3, 2, 0, false, true><<<nTok / 16, 256, 0, stream>>>(
                U, out_w + (size_t)i * DIMc * DINNERc, nullptr, xrs, 384);
            ln_k<<<nTok, 64, 0, stream>>>(xrs, ff_ln_s + i * DIMc, ff_ln_b + i * DIMc, T4);
            gemm_big<384, 768, 3, 1, 1, true, false><<<nTok / 8, 256, 0, stream>>>(
                T4, ff_w1 + (size_t)i * HIDc * DIMc, ff_b1 + (size_t)i * HIDc, XZ, 768);
            gemm_big<768, 384, 3, 2, 0, true, true><<<nTok / 16, 256, 0, stream>>>(
                XZ, ff_w2 + (size_t)i * DIMc * HIDc, ff_b2 + (size_t)i * DIMc, xrs, 384);
        }
        ln_k<<<nTok, 64, 0, stream>>>(xrs, lno_s, lno_b, xrs);   // in-place final LN
    }
}

// Round 5
// 23396.786 us; speedup vs baseline: 2.8036x; 2.2950x over previous
//
#include <hip/hip_runtime.h>
#include <cstdint>
#include <cstddef>

// Problem constants
constexpr int Bc = 8, Lc = 4096, DIMc = 384;
constexpr int DSTATEc = 16, DCONVc = 4;
constexpr int DINNERc = 768, DTRANKc = 24, HIDc = 768;
constexpr float EPSc = 1e-5f;
// Scan chunking
constexpr int NCc = 16, TCc = Lc / NCc;   // 16 chunks of 256 steps

// ---------------------------------------------------------------------------
__global__ __launch_bounds__(256)
void add_pos_k(const float* __restrict__ x, const float* __restrict__ pos,
               float* __restrict__ xres, int nElem) {
    int i = blockIdx.x * 256 + threadIdx.x;
    if (i >= nElem) return;
    int pi = i % (Lc * DIMc);
    xres[i] = x[i] + pos[pi];
}

// ---------------------------------------------------------------------------
// LayerNorm over DIM=384.  4 tokens per block, one wave per token.
// Safe in-place (X==Y): every store depends on all loads through r.
__global__ __launch_bounds__(256)
void ln_k(const float* __restrict__ X, const float* __restrict__ s, const float* __restrict__ bb,
          float* __restrict__ Y) {
    int token = blockIdx.x * 4 + (threadIdx.x >> 6);
    int tid = threadIdx.x & 63;
    const float* xr = X + (size_t)token * DIMc;
    float v[6];
    float sum = 0.f;
#pragma unroll
    for (int j = 0; j < 6; j++) { v[j] = xr[tid + j * 64]; sum += v[j]; }
#pragma unroll
    for (int off = 32; off > 0; off >>= 1) sum += __shfl_xor(sum, off);
    float mean = sum * (1.f / DIMc);
    float var = 0.f;
#pragma unroll
    for (int j = 0; j < 6; j++) { float d = v[j] - mean; var += d * d; }
#pragma unroll
    for (int off = 32; off > 0; off >>= 1) var += __shfl_xor(var, off);
    var *= (1.f / DIMc);
    float r = rsqrtf(var + EPSc);
    float* yr = Y + (size_t)token * DIMc;
#pragma unroll
    for (int j = 0; j < 6; j++) {
        int c = tid + j * 64;
        yr[c] = (v[j] - mean) * r * s[c] + bb[c];
    }
}

// ---------------------------------------------------------------------------
// Tiled fp32 GEMM: Y[m,n] = act( sum_k X[m,k] W[n,k] + bias[n] ), ldx == K.
// 128x128 tile, BK=32, 256 threads, 8x8 acc/thread.  X and W staged in LDS
// transposed [k][m] (pad 132: write conflicts ~2-way, read 4-way only on W).
// Register prefetch of next k-tile overlaps global latency with FMA.
template<int K, int ACT, bool HAS_BIAS, bool ADD_RESID>
__global__ __launch_bounds__(256)
void gemm_tile(const float* __restrict__ X, const float* __restrict__ W,
               const float* __restrict__ bias, float* __restrict__ Y, int ldy) {
    constexpr int NT = K / 32;
    __shared__ __align__(16) float Xs[32][132];
    __shared__ __align__(16) float Ws[32][132];
    const int tid = threadIdx.x;
    const int m0 = blockIdx.x * 128;
    const int n0 = blockIdx.y * 128;
    const int lm = tid >> 3;          // 0..31 (row within load pass)
    const int lk = (tid & 7) * 4;     // 0,4,...,28
    const int tx = tid & 15;          // n-group (reads conflict; epilogue coalesces)
    const int ty = tid >> 4;          // m-group (broadcast reads)

    float xr[4][4], wr[4][4];
#pragma unroll
    for (int p = 0; p < 4; p++) {
        *(float4*)xr[p] = *(const float4*)(X + (size_t)(m0 + lm + p * 32) * K + lk);
        *(float4*)wr[p] = *(const float4*)(W + (size_t)(n0 + lm + p * 32) * K + lk);
    }
    float acc[8][8];
#pragma unroll
    for (int i = 0; i < 8; i++)
#pragma unroll
        for (int j = 0; j < 8; j++) acc[i][j] = 0.f;

    for (int kt = 0; kt < NT; kt++) {
        __syncthreads();
#pragma unroll
        for (int p = 0; p < 4; p++)
#pragma unroll
            for (int j = 0; j < 4; j++) {
                Xs[lk + j][lm + p * 32] = xr[p][j];
                Ws[lk + j][lm + p * 32] = wr[p][j];
            }
        __syncthreads();
        if (kt + 1 < NT) {
            const int k0 = (kt + 1) * 32;
#pragma unroll
            for (int p = 0; p < 4; p++) {
                *(float4*)xr[p] = *(const float4*)(X + (size_t)(m0 + lm + p * 32) * K + k0 + lk);
                *(float4*)wr[p] = *(const float4*)(W + (size_t)(n0 + lm + p * 32) * K + k0 + lk);
            }
        }
#pragma unroll 8
        for (int k = 0; k < 32; k++) {
            float xf[8], wf[8];
            *(float4*)&xf[0] = *(const float4*)&Xs[k][ty * 8];
            *(float4*)&xf[4] = *(const float4*)&Xs[k][ty * 8 + 4];
            *(float4*)&wf[0] = *(const float4*)&Ws[k][tx * 8];
            *(float4*)&wf[4] = *(const float4*)&Ws[k][tx * 8 + 4];
#pragma unroll
            for (int i = 0; i < 8; i++)
#pragma unroll
                for (int j = 0; j < 8; j++)
                    acc[i][j] += xf[i] * wf[j];
        }
    }
#pragma unroll
    for (int i = 0; i < 8; i++) {
        int row = m0 + ty * 8 + i;
        size_t base = (size_t)row * ldy + n0 + tx * 8;
#pragma unroll
        for (int j = 0; j < 8; j++) {
            float v = acc[i][j] + (HAS_BIAS ? bias[n0 + tx * 8 + j] : 0.f);
            if (ACT == 1) {
                float c = v + 0.044715f * v * v * v;
                float th = tanhf(0.7978845608028654f * c);
                v = 0.5f * v * (1.f + th);
            }
            if (ADD_RESID) Y[base + j] += v;
            else           Y[base + j] = v;
        }
    }
}

// ---------------------------------------------------------------------------
// xproj (E=56, K=768): 4 tokens/block, one wave per token, lane = e (<56).
__global__ __launch_bounds__(256)
void xproj_k(const float* __restrict__ X, const float* __restrict__ W,
             float* __restrict__ DBL) {
    __shared__ float xs[4][768];
    int m0 = blockIdx.x * 4;
    int tid = threadIdx.x;
    for (int idx = tid; idx < 4 * 768; idx += 256) {
        int m = idx / 768, k = idx - m * 768;
        xs[m][k] = X[(size_t)(m0 + m) * 768 + k];
    }
    __syncthreads();
    int m = tid >> 6;
    int e = tid & 63;
    if (e < 56) {
        const float* wr = W + (size_t)e * 768;
        float acc = 0.f;
        for (int k = 0; k < 768; k += 4) {
            float4 xv = *reinterpret_cast<const float4*>(&xs[m][k]);
            float4 wv = *reinterpret_cast<const float4*>(wr + k);
            acc += xv.x * wv.x + xv.y * wv.y + xv.z * wv.z + xv.w * wv.w;
        }
        DBL[(size_t)(m0 + m) * 56 + e] = acc;
    }
}

// ---------------------------------------------------------------------------
__global__ __launch_bounds__(256)
void conv_k(const float* __restrict__ xz, const float* __restrict__ cw, const float* __restrict__ cb,
            float* __restrict__ u, int nElem) {
    int i = blockIdx.x * 256 + threadIdx.x;
    if (i >= nElem) return;
    int d = i % DINNERc;
    int token = i / DINNERc;
    int t = token % Lc;
    float acc = cb[d];
#pragma unroll
    for (int k = 0; k < DCONVc; k++) {
        int tt = t + k - (DCONVc - 1);
        if (tt >= 0)
            acc += xz[(size_t)(token + k - (DCONVc - 1)) * (2 * DINNERc) + d] * cw[d * DCONVc + k];
    }
    u[i] = acc / (1.f + expf(-acc));   // silu
}

// ---------------------------------------------------------------------------
__global__ __launch_bounds__(256)
void dtproj_k(const float* __restrict__ dbl, const float* __restrict__ dtw,
              const float* __restrict__ dtb, float* __restrict__ out, int nElem) {
    int i = blockIdx.x * 256 + threadIdx.x;
    if (i >= nElem) return;
    int d = i % DINNERc;
    int token = i / DINNERc;
    const float* row = dbl + (size_t)token * 56;
    const float* wr = dtw + (size_t)d * DTRANKc;
    float acc = dtb[d];
#pragma unroll
    for (int r = 0; r < DTRANKc; r++) acc += row[r] * wr[r];
    float sp = fmaxf(acc, 0.f) + log1pf(expf(-fabsf(acc)));
    out[(size_t)token * (2 * DINNERc) + d] = sp;
}

// ---------------------------------------------------------------------------
// Scan pass 1: per (b,d,s,chunk) compute P = prod(dA) and local h (h0=0).
__global__ __launch_bounds__(256)
void scan1_k(const float* __restrict__ dtb, const float* __restrict__ ub,
             const float* __restrict__ dblb, const float* __restrict__ A_log,
             float* __restrict__ Pb, float* __restrict__ Hb) {
    int g = blockIdx.x * 256 + threadIdx.x;
    int s = g & 15;
    int c = (g >> 4) & (NCc - 1);
    int d = (g >> 8) % DINNERc;
    int b = g / (DINNERc * DSTATEc * NCc);
    float a = -expf(A_log[d * DSTATEc + s]);
    size_t row0 = (size_t)b * Lc + c * TCc;
    const float* dtp = dtb + row0 * (2 * DINNERc) + d;
    const float* up  = ub  + row0 * DINNERc + d;
    const float* Bp  = dblb + row0 * 56 + DTRANKc + s;
    float h = 0.f, P = 1.f;
    for (int t = 0; t < TCc; t++) {
        float dt = *dtp, uv = *up, Bv = *Bp;
        float dA = __expf(dt * a);
        h = h * dA + dt * uv * Bv;
        P *= dA;
        dtp += 2 * DINNERc; up += DINNERc; Bp += 56;
    }
    size_t sidx = (((size_t)b * DINNERc + d) * DSTATEc + s) * NCc + c;
    Pb[sidx] = P;
    Hb[sidx] = h;
}

// Scan pass 2: sequential combine over NC chunks per (b,d,s).
__global__ __launch_bounds__(256)
void scan2_k(const float* __restrict__ Pb, const float* __restrict__ Hb,
             float* __restrict__ H0b, int nSeq) {
    int j = blockIdx.x * 256 + threadIdx.x;
    if (j >= nSeq) return;
    size_t base = (size_t)j * NCc;
    float h0 = 0.f;
#pragma unroll
    for (int c = 0; c < NCc; c++) {
        H0b[base + c] = h0;
        h0 = h0 * Pb[base + c] + Hb[base + c];
    }
}

// Scan pass 3: re-run chunk from h0, reduce over s (16-lane shfl), gate, store.
// yb == ub (in-place; lanes read u before lane 0 writes y, same wave).
__global__ __launch_bounds__(256)
void scan3_k(const float* __restrict__ dtb, const float* ub,
             const float* __restrict__ dblb, const float* __restrict__ zb,
             const float* __restrict__ A_log, const float* __restrict__ Dp,
             const float* __restrict__ H0b, float* yb) {
    int g = blockIdx.x * 256 + threadIdx.x;
    int s = g & 15;
    int c = (g >> 4) & (NCc - 1);
    int d = (g >> 8) % DINNERc;
    int b = g / (DINNERc * DSTATEc * NCc);
    float a = -expf(A_log[d * DSTATEc + s]);
    float Dv = Dp[d];
    size_t sidx = (((size_t)b * DINNERc + d) * DSTATEc + s) * NCc + c;
    float h = H0b[sidx];
    size_t row0 = (size_t)b * Lc + c * TCc;
    const float* dtp = dtb + row0 * (2 * DINNERc) + d;
    const float* up  = ub  + row0 * DINNERc + d;
    const float* Bp  = dblb + row0 * 56 + DTRANKc + s;
    const float* Cp  = dblb + row0 * 56 + DTRANKc + DSTATEc + s;
    const float* zp  = zb + row0 * (2 * DINNERc) + DINNERc + d;
    float* yp = yb + row0 * DINNERc + d;
    for (int t = 0; t < TCc; t++) {
        float dt = *dtp, uv = *up, Bv = *Bp, Cv = *Cp;
        float dA = __expf(dt * a);
        h = h * dA + dt * uv * Bv;
        float y = h * Cv;
        y += __shfl_xor(y, 1);
        y += __shfl_xor(y, 2);
        y += __shfl_xor(y, 4);
        y += __shfl_xor(y, 8);
        if (s == 0) {
            float zv = *zp;
            *yp = (y + uv * Dv) * (zv / (1.f + __expf(-zv)));
        }
        dtp += 2 * DINNERc; up += DINNERc; Bp += 56; Cp += 56;
        zp += 2 * DINNERc; yp += DINNERc;
    }
}

// ---------------------------------------------------------------------------
extern "C" void kernel_launch(void* const* d_in, const int* in_sizes, int n_in,
                              void* d_out, int out_size, void* d_ws, size_t ws_size,
                              hipStream_t stream) {
    const float* x        = (const float*)d_in[0];
    const float* pos      = (const float*)d_in[1];
    const float* ln1_s    = (const float*)d_in[2];
    const float* ln1_b    = (const float*)d_in[3];
    const float* in_w     = (const float*)d_in[4];
    const float* conv_w   = (const float*)d_in[5];
    const float* conv_b   = (const float*)d_in[6];
    const float* xproj_w  = (const float*)d_in[7];
    const float* dtproj_w = (const float*)d_in[8];
    const float* dtproj_b = (const float*)d_in[9];
    const float* A_log    = (const float*)d_in[10];
    const float* Dp       = (const float*)d_in[11];
    const float* out_w    = (const float*)d_in[12];
    const float* ff_ln_s  = (const float*)d_in[13];
    const float* ff_ln_b  = (const float*)d_in[14];
    const float* ff_w1    = (const float*)d_in[15];
    const float* ff_b1    = (const float*)d_in[16];
    const float* ff_w2    = (const float*)d_in[17];
    const float* ff_b2    = (const float*)d_in[18];
    const float* lno_s    = (const float*)d_in[19];
    const float* lno_b    = (const float*)d_in[20];
    float* out            = (float*)d_out;

    // Residual stream lives in d_out (fp32, full size).
    float* xres = out;

    const size_t perB = (size_t)Lc * 2 * DINNERc * 4 + (size_t)Lc * DINNERc * 4
                      + (size_t)Lc * DIMc * 4 + 3ull * DINNERc * DSTATEc * NCc * 4;
    int cb = (int)(ws_size / perB);
    if (cb < 1) cb = 1;
    if (cb > Bc) cb = Bc;

    char* p = (char*)d_ws;
    float* XZ = (float*)p;  p += (size_t)cb * Lc * 2 * DINNERc * 4;
    float* U  = (float*)p;  p += (size_t)cb * Lc * DINNERc * 4;
    float* T4 = (float*)p;  p += (size_t)cb * Lc * DIMc * 4;     // also hosts DBL (ld 56)
    float* SP = (float*)p;  p += (size_t)cb * DINNERc * DSTATEc * NCc * 4;
    float* SH = (float*)p;  p += (size_t)cb * DINNERc * DSTATEc * NCc * 4;
    float* SH0 = (float*)p;
    float* DBL = T4;

    add_pos_k<<<(Bc * Lc * DIMc + 255) / 256, 256, 0, stream>>>(
        x, pos, xres, Bc * Lc * DIMc);

    for (int b0 = 0; b0 < Bc; b0 += cb) {
        int cbc = (Bc - b0 < cb) ? (Bc - b0) : cb;
        int nTok = cbc * Lc;
        float* xrs = xres + (size_t)b0 * Lc * DIMc;

        for (int i = 0; i < 6; i++) {
            ln_k<<<nTok / 4, 256, 0, stream>>>(xrs, ln1_s + i * DIMc, ln1_b + i * DIMc, T4);
            gemm_tile<384, 0, false, false><<<dim3(nTok / 128, 12), 256, 0, stream>>>(
                T4, in_w + (size_t)i * 2 * DINNERc * DIMc, nullptr, XZ, 1536);
            conv_k<<<nTok * DINNERc / 256, 256, 0, stream>>>(
                XZ, conv_w + (size_t)i * DINNERc * DCONVc, conv_b + (size_t)i * DINNERc,
                U, nTok * DINNERc);
            xproj_k<<<nTok / 4, 256, 0, stream>>>(
                U, xproj_w + (size_t)i * 56 * DINNERc, DBL);
            dtproj_k<<<nTok * DINNERc / 256, 256, 0, stream>>>(
                DBL, dtproj_w + (size_t)i * DINNERc * DTRANKc, dtproj_b + (size_t)i * DINNERc,
                XZ, nTok * DINNERc);
            scan1_k<<<cbc * DINNERc, 256, 0, stream>>>(
                XZ, U, DBL, A_log + (size_t)i * DINNERc * DSTATEc, SP, SH);
            scan2_k<<<(cbc * DINNERc * DSTATEc + 255) / 256, 256, 0, stream>>>(
                SP, SH, SH0, cbc * DINNERc * DSTATEc);
            scan3_k<<<cbc * DINNERc, 256, 0, stream>>>(
                XZ, U, DBL, XZ, A_log + (size_t)i * DINNERc * DSTATEc,
                Dp + (size_t)i * DINNERc, SH0, U);
            gemm_tile<768, 0, false, true><<<dim3(nTok / 128, 3), 256, 0, stream>>>(
                U, out_w + (size_t)i * DIMc * DINNERc, nullptr, xrs, 384);
            ln_k<<<nTok / 4, 256, 0, stream>>>(xrs, ff_ln_s + i * DIMc, ff_ln_b + i * DIMc, T4);
            gemm_tile<384, 1, true, false><<<dim3(nTok / 128, 6), 256, 0, stream>>>(
                T4, ff_w1 + (size_t)i * HIDc * DIMc, ff_b1 + (size_t)i * HIDc, XZ, 768);
            gemm_tile<768, 0, true, true><<<dim3(nTok / 128, 3), 256, 0, stream>>>(
                XZ, ff_w2 + (size_t)i * DIMc * HIDc, ff_b2 + (size_t)i * DIMc, xrs, 384);
        }
        ln_k<<<nTok / 4, 256, 0, stream>>>(xrs, lno_s, lno_b, xrs);   // in-place final LN
    }
}

// Round 6
// 17544.412 us; speedup vs baseline: 3.7388x; 1.3336x over previous
//
#include <hip/hip_runtime.h>
#include <cstdint>
#include <cstddef>

// Problem constants
constexpr int Bc = 8, Lc = 4096, DIMc = 384;
constexpr int DSTATEc = 16, DCONVc = 4;
constexpr int DINNERc = 768, DTRANKc = 24, HIDc = 768;
constexpr float EPSc = 1e-5f;
// Scan chunking
constexpr int NCc = 16, TCc = Lc / NCc;   // 16 chunks of 256 steps

// ---------------------------------------------------------------------------
__global__ __launch_bounds__(256)
void add_pos_k(const float* __restrict__ x, const float* __restrict__ pos,
               float* __restrict__ xres, int nElem) {
    int i = blockIdx.x * 256 + threadIdx.x;
    if (i >= nElem) return;
    int pi = i % (Lc * DIMc);
    xres[i] = x[i] + pos[pi];
}

// ---------------------------------------------------------------------------
// LayerNorm over DIM=384.  4 tokens per block, one wave per token.
__global__ __launch_bounds__(256)
void ln_k(const float* __restrict__ X, const float* __restrict__ s, const float* __restrict__ bb,
          float* __restrict__ Y) {
    int token = blockIdx.x * 4 + (threadIdx.x >> 6);
    int tid = threadIdx.x & 63;
    const float* xr = X + (size_t)token * DIMc;
    float v[6];
    float sum = 0.f;
#pragma unroll
    for (int j = 0; j < 6; j++) { v[j] = xr[tid + j * 64]; sum += v[j]; }
#pragma unroll
    for (int off = 32; off > 0; off >>= 1) sum += __shfl_xor(sum, off);
    float mean = sum * (1.f / DIMc);
    float var = 0.f;
#pragma unroll
    for (int j = 0; j < 6; j++) { float d = v[j] - mean; var += d * d; }
#pragma unroll
    for (int off = 32; off > 0; off >>= 1) var += __shfl_xor(var, off);
    var *= (1.f / DIMc);
    float r = rsqrtf(var + EPSc);
    float* yr = Y + (size_t)token * DIMc;
#pragma unroll
    for (int j = 0; j < 6; j++) {
        int c = tid + j * 64;
        yr[c] = (v[j] - mean) * r * s[c] + bb[c];
    }
}

// ---------------------------------------------------------------------------
// Tiled fp32 GEMM: Y[m,n] = act( sum_k X[m,k] W[n,k] + bias[n] ), ldx == K.
// 128x128 tile, BK=32, 256 threads, 8x8 acc/thread.
template<int K, int ACT, bool HAS_BIAS, bool ADD_RESID>
__global__ __launch_bounds__(256)
void gemm_tile(const float* __restrict__ X, const float* __restrict__ W,
               const float* __restrict__ bias, float* __restrict__ Y, int ldy) {
    constexpr int NT = K / 32;
    __shared__ __align__(16) float Xs[32][132];
    __shared__ __align__(16) float Ws[32][132];
    const int tid = threadIdx.x;
    const int m0 = blockIdx.x * 128;
    const int n0 = blockIdx.y * 128;
    const int lm = tid >> 3;
    const int lk = (tid & 7) * 4;
    const int tx = tid & 15;
    const int ty = tid >> 4;

    float xr[4][4], wr[4][4];
#pragma unroll
    for (int p = 0; p < 4; p++) {
        *(float4*)xr[p] = *(const float4*)(X + (size_t)(m0 + lm + p * 32) * K + lk);
        *(float4*)wr[p] = *(const float4*)(W + (size_t)(n0 + lm + p * 32) * K + lk);
    }
    float acc[8][8];
#pragma unroll
    for (int i = 0; i < 8; i++)
#pragma unroll
        for (int j = 0; j < 8; j++) acc[i][j] = 0.f;

    for (int kt = 0; kt < NT; kt++) {
        __syncthreads();
#pragma unroll
        for (int p = 0; p < 4; p++)
#pragma unroll
            for (int j = 0; j < 4; j++) {
                Xs[lk + j][lm + p * 32] = xr[p][j];
                Ws[lk + j][lm + p * 32] = wr[p][j];
            }
        __syncthreads();
        if (kt + 1 < NT) {
            const int k0 = (kt + 1) * 32;
#pragma unroll
            for (int p = 0; p < 4; p++) {
                *(float4*)xr[p] = *(const float4*)(X + (size_t)(m0 + lm + p * 32) * K + k0 + lk);
                *(float4*)wr[p] = *(const float4*)(W + (size_t)(n0 + lm + p * 32) * K + k0 + lk);
            }
        }
#pragma unroll 8
        for (int k = 0; k < 32; k++) {
            float xf[8], wf[8];
            *(float4*)&xf[0] = *(const float4*)&Xs[k][ty * 8];
            *(float4*)&xf[4] = *(const float4*)&Xs[k][ty * 8 + 4];
            *(float4*)&wf[0] = *(const float4*)&Ws[k][tx * 8];
            *(float4*)&wf[4] = *(const float4*)&Ws[k][tx * 8 + 4];
#pragma unroll
            for (int i = 0; i < 8; i++)
#pragma unroll
                for (int j = 0; j < 8; j++)
                    acc[i][j] += xf[i] * wf[j];
        }
    }
#pragma unroll
    for (int i = 0; i < 8; i++) {
        int row = m0 + ty * 8 + i;
        size_t base = (size_t)row * ldy + n0 + tx * 8;
#pragma unroll
        for (int j = 0; j < 8; j++) {
            float v = acc[i][j] + (HAS_BIAS ? bias[n0 + tx * 8 + j] : 0.f);
            if (ACT == 1) {
                float c = v + 0.044715f * v * v * v;
                float th = tanhf(0.7978845608028654f * c);
                v = 0.5f * v * (1.f + th);
            }
            if (ADD_RESID) Y[base + j] += v;
            else           Y[base + j] = v;
        }
    }
}

// ---------------------------------------------------------------------------
// xproj (E=56, K=768): 4 tokens/block, one wave per token, lane = e (<56).
__global__ __launch_bounds__(256)
void xproj_k(const float* __restrict__ X, const float* __restrict__ W,
             float* __restrict__ DBL) {
    __shared__ float xs[4][768];
    int m0 = blockIdx.x * 4;
    int tid = threadIdx.x;
    for (int idx = tid; idx < 4 * 768; idx += 256) {
        int m = idx / 768, k = idx - m * 768;
        xs[m][k] = X[(size_t)(m0 + m) * 768 + k];
    }
    __syncthreads();
    int m = tid >> 6;
    int e = tid & 63;
    if (e < 56) {
        const float* wr = W + (size_t)e * 768;
        float acc = 0.f;
        for (int k = 0; k < 768; k += 4) {
            float4 xv = *reinterpret_cast<const float4*>(&xs[m][k]);
            float4 wv = *reinterpret_cast<const float4*>(wr + k);
            acc += xv.x * wv.x + xv.y * wv.y + xv.z * wv.z + xv.w * wv.w;
        }
        DBL[(size_t)(m0 + m) * 56 + e] = acc;
    }
}

// ---------------------------------------------------------------------------
__global__ __launch_bounds__(256)
void conv_k(const float* __restrict__ xz, const float* __restrict__ cw, const float* __restrict__ cb,
            float* __restrict__ u, int nElem) {
    int i = blockIdx.x * 256 + threadIdx.x;
    if (i >= nElem) return;
    int d = i % DINNERc;
    int token = i / DINNERc;
    int t = token % Lc;
    float acc = cb[d];
#pragma unroll
    for (int k = 0; k < DCONVc; k++) {
        int tt = t + k - (DCONVc - 1);
        if (tt >= 0)
            acc += xz[(size_t)(token + k - (DCONVc - 1)) * (2 * DINNERc) + d] * cw[d * DCONVc + k];
    }
    u[i] = acc / (1.f + expf(-acc));   // silu
}

// ---------------------------------------------------------------------------
__global__ __launch_bounds__(256)
void dtproj_k(const float* __restrict__ dbl, const float* __restrict__ dtw,
              const float* __restrict__ dtb, float* __restrict__ out, int nElem) {
    int i = blockIdx.x * 256 + threadIdx.x;
    if (i >= nElem) return;
    int d = i % DINNERc;
    int token = i / DINNERc;
    const float* row = dbl + (size_t)token * 56;
    const float* wr = dtw + (size_t)d * DTRANKc;
    float acc = dtb[d];
#pragma unroll
    for (int r = 0; r < DTRANKc; r++) acc += row[r] * wr[r];
    float sp = fmaxf(acc, 0.f) + log1pf(expf(-fabsf(acc)));
    out[(size_t)token * (2 * DINNERc) + d] = sp;
}

// ---------------------------------------------------------------------------
// Scan, channel-parallel layout.  Block = (b, chunk c, d-group); thread = one
// d channel (coalesced dt/u/z/y); all 16 states in registers.  B/C rows are
// wave-uniform float4 broadcast loads.  State buffers laid out [b][c][d][s]
// (each thread owns 64B contiguous -> dense wave stores).
// Pass 1: local h (h0=0) and P[s] = exp(a_s * sum(dt)).
__global__ __launch_bounds__(256)
void scan1_k(const float* __restrict__ dtb, const float* __restrict__ ub,
             const float* __restrict__ dblb, const float* __restrict__ A_log,
             float* __restrict__ Pb, float* __restrict__ Hb) {
    int blk = blockIdx.x;
    int dg = blk % 3;
    int c  = (blk / 3) % NCc;
    int b  = blk / (3 * NCc);
    int d  = dg * 256 + threadIdx.x;

    float a[16];
#pragma unroll
    for (int q = 0; q < 4; q++)
        *(float4*)&a[q * 4] = *(const float4*)(A_log + (size_t)d * 16 + q * 4);
#pragma unroll
    for (int s = 0; s < 16; s++) a[s] = -__expf(a[s]);

    float h[16];
#pragma unroll
    for (int s = 0; s < 16; s++) h[s] = 0.f;
    float Sdt = 0.f;

    size_t row0 = (size_t)b * Lc + c * TCc;
    const float* dtp = dtb + row0 * (2 * DINNERc) + d;
    const float* up  = ub  + row0 * DINNERc + d;
    const float* Bp  = dblb + row0 * 56 + DTRANKc;
    for (int t = 0; t < TCc; t++) {
        float dt = *dtp, uv = *up;
        float Bv[16];
#pragma unroll
        for (int q = 0; q < 4; q++)
            *(float4*)&Bv[q * 4] = *(const float4*)(Bp + q * 4);
        float du = dt * uv;
        Sdt += dt;
#pragma unroll
        for (int s = 0; s < 16; s++)
            h[s] = h[s] * __expf(dt * a[s]) + du * Bv[s];
        dtp += 2 * DINNERc; up += DINNERc; Bp += 56;
    }
    size_t base = (((size_t)b * NCc + c) * DINNERc + d) * 16;
#pragma unroll
    for (int q = 0; q < 4; q++) {
        float4 pv;
        pv.x = __expf(Sdt * a[q * 4 + 0]);
        pv.y = __expf(Sdt * a[q * 4 + 1]);
        pv.z = __expf(Sdt * a[q * 4 + 2]);
        pv.w = __expf(Sdt * a[q * 4 + 3]);
        *(float4*)(Pb + base + q * 4) = pv;
        *(float4*)(Hb + base + q * 4) = *(const float4*)&h[q * 4];
    }
}

// Pass 2: sequential combine over NC chunks per (b,d,s).  Layout [b][c][d][s];
// consecutive threads (s fastest) read consecutive addresses each c-step.
__global__ __launch_bounds__(256)
void scan2_k(const float* __restrict__ Pb, const float* __restrict__ Hb,
             float* __restrict__ H0b, int nSeq) {
    int j = blockIdx.x * 256 + threadIdx.x;
    if (j >= nSeq) return;
    int s = j & 15;
    int d = (j >> 4) % DINNERc;
    int b = j / (DINNERc * 16);
    float h0 = 0.f;
#pragma unroll
    for (int c = 0; c < NCc; c++) {
        size_t idx = (((size_t)b * NCc + c) * DINNERc + d) * 16 + s;
        H0b[idx] = h0;
        h0 = h0 * Pb[idx] + Hb[idx];
    }
}

// Pass 3: re-run chunk from h0, y = sum_s h*C (in registers), gate, store.
// yb == ub in-place: each thread reads u then writes y at the SAME address.
__global__ __launch_bounds__(256)
void scan3_k(const float* __restrict__ dtb, const float* ub,
             const float* __restrict__ dblb, const float* __restrict__ zb,
             const float* __restrict__ A_log, const float* __restrict__ Dp,
             const float* __restrict__ H0b, float* yb) {
    int blk = blockIdx.x;
    int dg = blk % 3;
    int c  = (blk / 3) % NCc;
    int b  = blk / (3 * NCc);
    int d  = dg * 256 + threadIdx.x;

    float a[16];
#pragma unroll
    for (int q = 0; q < 4; q++)
        *(float4*)&a[q * 4] = *(const float4*)(A_log + (size_t)d * 16 + q * 4);
#pragma unroll
    for (int s = 0; s < 16; s++) a[s] = -__expf(a[s]);
    float Dv = Dp[d];

    float h[16];
    size_t sbase = (((size_t)b * NCc + c) * DINNERc + d) * 16;
#pragma unroll
    for (int q = 0; q < 4; q++)
        *(float4*)&h[q * 4] = *(const float4*)(H0b + sbase + q * 4);

    size_t row0 = (size_t)b * Lc + c * TCc;
    const float* dtp = dtb + row0 * (2 * DINNERc) + d;
    const float* up  = ub  + row0 * DINNERc + d;
    const float* BCp = dblb + row0 * 56 + DTRANKc;
    const float* zp  = zb + row0 * (2 * DINNERc) + DINNERc + d;
    float* yp = yb + row0 * DINNERc + d;
    for (int t = 0; t < TCc; t++) {
        float dt = *dtp, uv = *up, zv = *zp;
        float Bv[16], Cv[16];
#pragma unroll
        for (int q = 0; q < 4; q++) {
            *(float4*)&Bv[q * 4] = *(const float4*)(BCp + q * 4);
            *(float4*)&Cv[q * 4] = *(const float4*)(BCp + 16 + q * 4);
        }
        float du = dt * uv;
        float y = 0.f;
#pragma unroll
        for (int s = 0; s < 16; s++) {
            h[s] = h[s] * __expf(dt * a[s]) + du * Bv[s];
            y += h[s] * Cv[s];
        }
        *yp = (y + uv * Dv) * (zv / (1.f + __expf(-zv)));
        dtp += 2 * DINNERc; up += DINNERc; BCp += 56;
        zp += 2 * DINNERc; yp += DINNERc;
    }
}

// ---------------------------------------------------------------------------
extern "C" void kernel_launch(void* const* d_in, const int* in_sizes, int n_in,
                              void* d_out, int out_size, void* d_ws, size_t ws_size,
                              hipStream_t stream) {
    const float* x        = (const float*)d_in[0];
    const float* pos      = (const float*)d_in[1];
    const float* ln1_s    = (const float*)d_in[2];
    const float* ln1_b    = (const float*)d_in[3];
    const float* in_w     = (const float*)d_in[4];
    const float* conv_w   = (const float*)d_in[5];
    const float* conv_b   = (const float*)d_in[6];
    const float* xproj_w  = (const float*)d_in[7];
    const float* dtproj_w = (const float*)d_in[8];
    const float* dtproj_b = (const float*)d_in[9];
    const float* A_log    = (const float*)d_in[10];
    const float* Dp       = (const float*)d_in[11];
    const float* out_w    = (const float*)d_in[12];
    const float* ff_ln_s  = (const float*)d_in[13];
    const float* ff_ln_b  = (const float*)d_in[14];
    const float* ff_w1    = (const float*)d_in[15];
    const float* ff_b1    = (const float*)d_in[16];
    const float* ff_w2    = (const float*)d_in[17];
    const float* ff_b2    = (const float*)d_in[18];
    const float* lno_s    = (const float*)d_in[19];
    const float* lno_b    = (const float*)d_in[20];
    float* out            = (float*)d_out;

    float* xres = out;   // residual stream lives in d_out (fp32, full size)

    const size_t perB = (size_t)Lc * 2 * DINNERc * 4 + (size_t)Lc * DINNERc * 4
                      + (size_t)Lc * DIMc * 4 + 3ull * DINNERc * DSTATEc * NCc * 4;
    int cb = (int)(ws_size / perB);
    if (cb < 1) cb = 1;
    if (cb > Bc) cb = Bc;

    char* p = (char*)d_ws;
    float* XZ = (float*)p;  p += (size_t)cb * Lc * 2 * DINNERc * 4;
    float* U  = (float*)p;  p += (size_t)cb * Lc * DINNERc * 4;
    float* T4 = (float*)p;  p += (size_t)cb * Lc * DIMc * 4;     // also hosts DBL (ld 56)
    float* SP = (float*)p;  p += (size_t)cb * DINNERc * DSTATEc * NCc * 4;
    float* SH = (float*)p;  p += (size_t)cb * DINNERc * DSTATEc * NCc * 4;
    float* SH0 = (float*)p;
    float* DBL = T4;

    add_pos_k<<<(Bc * Lc * DIMc + 255) / 256, 256, 0, stream>>>(
        x, pos, xres, Bc * Lc * DIMc);

    for (int b0 = 0; b0 < Bc; b0 += cb) {
        int cbc = (Bc - b0 < cb) ? (Bc - b0) : cb;
        int nTok = cbc * Lc;
        float* xrs = xres + (size_t)b0 * Lc * DIMc;

        for (int i = 0; i < 6; i++) {
            ln_k<<<nTok / 4, 256, 0, stream>>>(xrs, ln1_s + i * DIMc, ln1_b + i * DIMc, T4);
            gemm_tile<384, 0, false, false><<<dim3(nTok / 128, 12), 256, 0, stream>>>(
                T4, in_w + (size_t)i * 2 * DINNERc * DIMc, nullptr, XZ, 1536);
            conv_k<<<nTok * DINNERc / 256, 256, 0, stream>>>(
                XZ, conv_w + (size_t)i * DINNERc * DCONVc, conv_b + (size_t)i * DINNERc,
                U, nTok * DINNERc);
            xproj_k<<<nTok / 4, 256, 0, stream>>>(
                U, xproj_w + (size_t)i * 56 * DINNERc, DBL);
            dtproj_k<<<nTok * DINNERc / 256, 256, 0, stream>>>(
                DBL, dtproj_w + (size_t)i * DINNERc * DTRANKc, dtproj_b + (size_t)i * DINNERc,
                XZ, nTok * DINNERc);
            scan1_k<<<cbc * NCc * 3, 256, 0, stream>>>(
                XZ, U, DBL, A_log + (size_t)i * DINNERc * DSTATEc, SP, SH);
            scan2_k<<<(cbc * DINNERc * DSTATEc + 255) / 256, 256, 0, stream>>>(
                SP, SH, SH0, cbc * DINNERc * DSTATEc);
            scan3_k<<<cbc * NCc * 3, 256, 0, stream>>>(
                XZ, U, DBL, XZ, A_log + (size_t)i * DINNERc * DSTATEc,
                Dp + (size_t)i * DINNERc, SH0, U);
            gemm_tile<768, 0, false, true><<<dim3(nTok / 128, 3), 256, 0, stream>>>(
                U, out_w + (size_t)i * DIMc * DINNERc, nullptr, xrs, 384);
            ln_k<<<nTok / 4, 256, 0, stream>>>(xrs, ff_ln_s + i * DIMc, ff_ln_b + i * DIMc, T4);
            gemm_tile<384, 1, true, false><<<dim3(nTok / 128, 6), 256, 0, stream>>>(
                T4, ff_w1 + (size_t)i * HIDc * DIMc, ff_b1 + (size_t)i * HIDc, XZ, 768);
            gemm_tile<768, 0, true, true><<<dim3(nTok / 128, 3), 256, 0, stream>>>(
                XZ, ff_w2 + (size_t)i * DIMc * HIDc, ff_b2 + (size_t)i * DIMc, xrs, 384);
        }
        ln_k<<<nTok / 4, 256, 0, stream>>>(xrs, lno_s, lno_b, xrs);   // in-place final LN
    }
}

// Round 7
// 8529.601 us; speedup vs baseline: 7.6904x; 2.0569x over previous
//
#include <hip/hip_runtime.h>
#include <cstdint>
#include <cstddef>

// Problem constants
constexpr int Bc = 8, Lc = 4096, DIMc = 384;
constexpr int DSTATEc = 16, DCONVc = 4;
constexpr int DINNERc = 768, DTRANKc = 24, HIDc = 768;
constexpr float EPSc = 1e-5f;
// Scan chunking
constexpr int NCc = 16, TCc = Lc / NCc;   // 16 chunks of 256 steps

typedef __attribute__((ext_vector_type(8))) short bf16x8;
typedef __attribute__((ext_vector_type(4))) float f32x4;

__device__ __forceinline__ unsigned int f2bf(float f) {
    union { float f; unsigned int u; } v; v.f = f;
    unsigned int u = v.u;
    u += 0x7fffu + ((u >> 16) & 1u);   // round-to-nearest-even
    return u >> 16;
}

// ---------------------------------------------------------------------------
__global__ __launch_bounds__(256)
void add_pos_k(const float* __restrict__ x, const float* __restrict__ pos,
               float* __restrict__ xres, int nElem) {
    int i = blockIdx.x * 256 + threadIdx.x;
    if (i >= nElem) return;
    int pi = i % (Lc * DIMc);
    xres[i] = x[i] + pos[pi];
}

// ---------------------------------------------------------------------------
// LayerNorm over DIM=384.  4 tokens per block, one wave per token.
__global__ __launch_bounds__(256)
void ln_k(const float* __restrict__ X, const float* __restrict__ s, const float* __restrict__ bb,
          float* __restrict__ Y) {
    int token = blockIdx.x * 4 + (threadIdx.x >> 6);
    int tid = threadIdx.x & 63;
    const float* xr = X + (size_t)token * DIMc;
    float v[6];
    float sum = 0.f;
#pragma unroll
    for (int j = 0; j < 6; j++) { v[j] = xr[tid + j * 64]; sum += v[j]; }
#pragma unroll
    for (int off = 32; off > 0; off >>= 1) sum += __shfl_xor(sum, off);
    float mean = sum * (1.f / DIMc);
    float var = 0.f;
#pragma unroll
    for (int j = 0; j < 6; j++) { float d = v[j] - mean; var += d * d; }
#pragma unroll
    for (int off = 32; off > 0; off >>= 1) var += __shfl_xor(var, off);
    var *= (1.f / DIMc);
    float r = rsqrtf(var + EPSc);
    float* yr = Y + (size_t)token * DIMc;
#pragma unroll
    for (int j = 0; j < 6; j++) {
        int c = tid + j * 64;
        yr[c] = (v[j] - mean) * r * s[c] + bb[c];
    }
}

// ---------------------------------------------------------------------------
// MFMA bf16 GEMM: Y[m,n] = act( sum_k X[m,k] W[n,k] + bias[n] ), ldx == K.
// 128x128 tile, BK=32, 256 threads (4 waves).  Wave computes 64x64 via a
// 4x4 grid of mfma_f32_16x16x32_bf16 (fp32 accum).  fp32 global -> bf16
// convert during LDS staging; LDS holds fragments in exact lane order
// ([tile16][lane][8 bf16]) so all frag reads are contiguous ds_read_b128.
// nmax: valid rows of W / cols of Y (B-rows clamped, stores guarded) —
// lets the same kernel serve xproj (N=56 padded to 128).
template<int K, int ACT, bool HAS_BIAS, bool ADD_RESID>
__global__ __launch_bounds__(256)
void gemm_mfma(const float* __restrict__ X, const float* __restrict__ W,
               const float* __restrict__ bias, float* __restrict__ Y,
               int ldy, int nmax) {
    constexpr int NT = K / 32;
    __shared__ uint4 ABs[1024];            // A: [0,512)  B: [512,1024)  16 KB
    const int tid = threadIdx.x;
    const int m0 = blockIdx.x * 128;
    const int n0 = blockIdx.y * 128;

    float aA[2][8], aB[2][8];
    auto load_tiles = [&](int kt) {
#pragma unroll
        for (int r = 0; r < 2; r++) {
            int p = tid + r * 256;
            int mt = p >> 6, l = p & 63;
            int kc = ((l >> 4) << 3) + kt * 32;
            int arow = m0 + mt * 16 + (l & 15);
            const float* ga = X + (size_t)arow * K + kc;
            *(float4*)&aA[r][0] = *(const float4*)ga;
            *(float4*)&aA[r][4] = *(const float4*)(ga + 4);
            int brow = n0 + mt * 16 + (l & 15);
            if (brow > nmax - 1) brow = nmax - 1;
            const float* gb = W + (size_t)brow * K + kc;
            *(float4*)&aB[r][0] = *(const float4*)gb;
            *(float4*)&aB[r][4] = *(const float4*)(gb + 4);
        }
    };

    f32x4 acc[4][4];
#pragma unroll
    for (int i = 0; i < 4; i++)
#pragma unroll
        for (int j = 0; j < 4; j++) acc[i][j] = {0.f, 0.f, 0.f, 0.f};

    const int lane = tid & 63;
    const int wv = tid >> 6;
    const int wy = wv >> 1, wx = wv & 1;
    const bf16x8* Af = (const bf16x8*)ABs;
    const bf16x8* Bf = Af + 512;

    load_tiles(0);
    for (int kt = 0; kt < NT; kt++) {
        __syncthreads();
#pragma unroll
        for (int r = 0; r < 2; r++) {
            int p = tid + r * 256;
            uint4 pa, pb;
            pa.x = f2bf(aA[r][0]) | (f2bf(aA[r][1]) << 16);
            pa.y = f2bf(aA[r][2]) | (f2bf(aA[r][3]) << 16);
            pa.z = f2bf(aA[r][4]) | (f2bf(aA[r][5]) << 16);
            pa.w = f2bf(aA[r][6]) | (f2bf(aA[r][7]) << 16);
            pb.x = f2bf(aB[r][0]) | (f2bf(aB[r][1]) << 16);
            pb.y = f2bf(aB[r][2]) | (f2bf(aB[r][3]) << 16);
            pb.z = f2bf(aB[r][4]) | (f2bf(aB[r][5]) << 16);
            pb.w = f2bf(aB[r][6]) | (f2bf(aB[r][7]) << 16);
            ABs[p] = pa;
            ABs[512 + p] = pb;
        }
        __syncthreads();
        if (kt + 1 < NT) load_tiles(kt + 1);
        bf16x8 a[4], b[4];
#pragma unroll
        for (int i = 0; i < 4; i++) a[i] = Af[(wy * 4 + i) * 64 + lane];
#pragma unroll
        for (int j = 0; j < 4; j++) b[j] = Bf[(wx * 4 + j) * 64 + lane];
#pragma unroll
        for (int i = 0; i < 4; i++)
#pragma unroll
            for (int j = 0; j < 4; j++)
                acc[i][j] = __builtin_amdgcn_mfma_f32_16x16x32_bf16(
                    a[i], b[j], acc[i][j], 0, 0, 0);
    }

    // Epilogue.  C/D layout: col = lane&15, row = (lane>>4)*4 + reg.
    const int colin = lane & 15;
    const int rquad = lane >> 4;
#pragma unroll
    for (int j = 0; j < 4; j++) {
        int col = n0 + wx * 64 + j * 16 + colin;
        if (col >= nmax) continue;
        float bv = HAS_BIAS ? bias[col] : 0.f;
#pragma unroll
        for (int i = 0; i < 4; i++) {
#pragma unroll
            for (int r = 0; r < 4; r++) {
                int row = m0 + wy * 64 + i * 16 + rquad * 4 + r;
                float v = acc[i][j][r] + bv;
                if (ACT == 1) {
                    float c = v + 0.044715f * v * v * v;
                    float th = tanhf(0.7978845608028654f * c);
                    v = 0.5f * v * (1.f + th);
                }
                size_t oi = (size_t)row * ldy + col;
                if (ADD_RESID) Y[oi] += v;
                else           Y[oi] = v;
            }
        }
    }
}

// ---------------------------------------------------------------------------
__global__ __launch_bounds__(256)
void conv_k(const float* __restrict__ xz, const float* __restrict__ cw, const float* __restrict__ cb,
            float* __restrict__ u, int nElem) {
    int i = blockIdx.x * 256 + threadIdx.x;
    if (i >= nElem) return;
    int d = i % DINNERc;
    int token = i / DINNERc;
    int t = token % Lc;
    float acc = cb[d];
#pragma unroll
    for (int k = 0; k < DCONVc; k++) {
        int tt = t + k - (DCONVc - 1);
        if (tt >= 0)
            acc += xz[(size_t)(token + k - (DCONVc - 1)) * (2 * DINNERc) + d] * cw[d * DCONVc + k];
    }
    u[i] = acc / (1.f + expf(-acc));   // silu
}

// ---------------------------------------------------------------------------
__global__ __launch_bounds__(256)
void dtproj_k(const float* __restrict__ dbl, const float* __restrict__ dtw,
              const float* __restrict__ dtb, float* __restrict__ out, int nElem) {
    int i = blockIdx.x * 256 + threadIdx.x;
    if (i >= nElem) return;
    int d = i % DINNERc;
    int token = i / DINNERc;
    const float* row = dbl + (size_t)token * 56;
    const float* wr = dtw + (size_t)d * DTRANKc;
    float acc = dtb[d];
#pragma unroll
    for (int r = 0; r < DTRANKc; r++) acc += row[r] * wr[r];
    float sp = fmaxf(acc, 0.f) + log1pf(expf(-fabsf(acc)));
    out[(size_t)token * (2 * DINNERc) + d] = sp;
}

// ---------------------------------------------------------------------------
// Scan, channel-parallel layout (round 6, verified).  Thread = one d channel,
// 16 states in registers, B/C wave-uniform broadcast, states [b][c][d][s].
__global__ __launch_bounds__(256)
void scan1_k(const float* __restrict__ dtb, const float* __restrict__ ub,
             const float* __restrict__ dblb, const float* __restrict__ A_log,
             float* __restrict__ Pb, float* __restrict__ Hb) {
    int blk = blockIdx.x;
    int dg = blk % 3;
    int c  = (blk / 3) % NCc;
    int b  = blk / (3 * NCc);
    int d  = dg * 256 + threadIdx.x;

    float a[16];
#pragma unroll
    for (int q = 0; q < 4; q++)
        *(float4*)&a[q * 4] = *(const float4*)(A_log + (size_t)d * 16 + q * 4);
#pragma unroll
    for (int s = 0; s < 16; s++) a[s] = -__expf(a[s]);

    float h[16];
#pragma unroll
    for (int s = 0; s < 16; s++) h[s] = 0.f;
    float Sdt = 0.f;

    size_t row0 = (size_t)b * Lc + c * TCc;
    const float* dtp = dtb + row0 * (2 * DINNERc) + d;
    const float* up  = ub  + row0 * DINNERc + d;
    const float* Bp  = dblb + row0 * 56 + DTRANKc;
    for (int t = 0; t < TCc; t++) {
        float dt = *dtp, uv = *up;
        float Bv[16];
#pragma unroll
        for (int q = 0; q < 4; q++)
            *(float4*)&Bv[q * 4] = *(const float4*)(Bp + q * 4);
        float du = dt * uv;
        Sdt += dt;
#pragma unroll
        for (int s = 0; s < 16; s++)
            h[s] = h[s] * __expf(dt * a[s]) + du * Bv[s];
        dtp += 2 * DINNERc; up += DINNERc; Bp += 56;
    }
    size_t base = (((size_t)b * NCc + c) * DINNERc + d) * 16;
#pragma unroll
    for (int q = 0; q < 4; q++) {
        float4 pv;
        pv.x = __expf(Sdt * a[q * 4 + 0]);
        pv.y = __expf(Sdt * a[q * 4 + 1]);
        pv.z = __expf(Sdt * a[q * 4 + 2]);
        pv.w = __expf(Sdt * a[q * 4 + 3]);
        *(float4*)(Pb + base + q * 4) = pv;
        *(float4*)(Hb + base + q * 4) = *(const float4*)&h[q * 4];
    }
}

__global__ __launch_bounds__(256)
void scan2_k(const float* __restrict__ Pb, const float* __restrict__ Hb,
             float* __restrict__ H0b, int nSeq) {
    int j = blockIdx.x * 256 + threadIdx.x;
    if (j >= nSeq) return;
    int s = j & 15;
    int d = (j >> 4) % DINNERc;
    int b = j / (DINNERc * 16);
    float h0 = 0.f;
#pragma unroll
    for (int c = 0; c < NCc; c++) {
        size_t idx = (((size_t)b * NCc + c) * DINNERc + d) * 16 + s;
        H0b[idx] = h0;
        h0 = h0 * Pb[idx] + Hb[idx];
    }
}

__global__ __launch_bounds__(256)
void scan3_k(const float* __restrict__ dtb, const float* ub,
             const float* __restrict__ dblb, const float* __restrict__ zb,
             const float* __restrict__ A_log, const float* __restrict__ Dp,
             const float* __restrict__ H0b, float* yb) {
    int blk = blockIdx.x;
    int dg = blk % 3;
    int c  = (blk / 3) % NCc;
    int b  = blk / (3 * NCc);
    int d  = dg * 256 + threadIdx.x;

    float a[16];
#pragma unroll
    for (int q = 0; q < 4; q++)
        *(float4*)&a[q * 4] = *(const float4*)(A_log + (size_t)d * 16 + q * 4);
#pragma unroll
    for (int s = 0; s < 16; s++) a[s] = -__expf(a[s]);
    float Dv = Dp[d];

    float h[16];
    size_t sbase = (((size_t)b * NCc + c) * DINNERc + d) * 16;
#pragma unroll
    for (int q = 0; q < 4; q++)
        *(float4*)&h[q * 4] = *(const float4*)(H0b + sbase + q * 4);

    size_t row0 = (size_t)b * Lc + c * TCc;
    const float* dtp = dtb + row0 * (2 * DINNERc) + d;
    const float* up  = ub  + row0 * DINNERc + d;
    const float* BCp = dblb + row0 * 56 + DTRANKc;
    const float* zp  = zb + row0 * (2 * DINNERc) + DINNERc + d;
    float* yp = yb + row0 * DINNERc + d;
    for (int t = 0; t < TCc; t++) {
        float dt = *dtp, uv = *up, zv = *zp;
        float Bv[16], Cv[16];
#pragma unroll
        for (int q = 0; q < 4; q++) {
            *(float4*)&Bv[q * 4] = *(const float4*)(BCp + q * 4);
            *(float4*)&Cv[q * 4] = *(const float4*)(BCp + 16 + q * 4);
        }
        float du = dt * uv;
        float y = 0.f;
#pragma unroll
        for (int s = 0; s < 16; s++) {
            h[s] = h[s] * __expf(dt * a[s]) + du * Bv[s];
            y += h[s] * Cv[s];
        }
        *yp = (y + uv * Dv) * (zv / (1.f + __expf(-zv)));
        dtp += 2 * DINNERc; up += DINNERc; BCp += 56;
        zp += 2 * DINNERc; yp += DINNERc;
    }
}

// ---------------------------------------------------------------------------
extern "C" void kernel_launch(void* const* d_in, const int* in_sizes, int n_in,
                              void* d_out, int out_size, void* d_ws, size_t ws_size,
                              hipStream_t stream) {
    const float* x        = (const float*)d_in[0];
    const float* pos      = (const float*)d_in[1];
    const float* ln1_s    = (const float*)d_in[2];
    const float* ln1_b    = (const float*)d_in[3];
    const float* in_w     = (const float*)d_in[4];
    const float* conv_w   = (const float*)d_in[5];
    const float* conv_b   = (const float*)d_in[6];
    const float* xproj_w  = (const float*)d_in[7];
    const float* dtproj_w = (const float*)d_in[8];
    const float* dtproj_b = (const float*)d_in[9];
    const float* A_log    = (const float*)d_in[10];
    const float* Dp       = (const float*)d_in[11];
    const float* out_w    = (const float*)d_in[12];
    const float* ff_ln_s  = (const float*)d_in[13];
    const float* ff_ln_b  = (const float*)d_in[14];
    const float* ff_w1    = (const float*)d_in[15];
    const float* ff_b1    = (const float*)d_in[16];
    const float* ff_w2    = (const float*)d_in[17];
    const float* ff_b2    = (const float*)d_in[18];
    const float* lno_s    = (const float*)d_in[19];
    const float* lno_b    = (const float*)d_in[20];
    float* out            = (float*)d_out;

    float* xres = out;   // residual stream lives in d_out (fp32, full size)

    const size_t perB = (size_t)Lc * 2 * DINNERc * 4 + (size_t)Lc * DINNERc * 4
                      + (size_t)Lc * DIMc * 4 + 3ull * DINNERc * DSTATEc * NCc * 4;
    int cb = (int)(ws_size / perB);
    if (cb < 1) cb = 1;
    if (cb > Bc) cb = Bc;

    char* p = (char*)d_ws;
    float* XZ = (float*)p;  p += (size_t)cb * Lc * 2 * DINNERc * 4;
    float* U  = (float*)p;  p += (size_t)cb * Lc * DINNERc * 4;
    float* T4 = (float*)p;  p += (size_t)cb * Lc * DIMc * 4;     // also hosts DBL (ld 56)
    float* SP = (float*)p;  p += (size_t)cb * DINNERc * DSTATEc * NCc * 4;
    float* SH = (float*)p;  p += (size_t)cb * DINNERc * DSTATEc * NCc * 4;
    float* SH0 = (float*)p;
    float* DBL = T4;

    add_pos_k<<<(Bc * Lc * DIMc + 255) / 256, 256, 0, stream>>>(
        x, pos, xres, Bc * Lc * DIMc);

    for (int b0 = 0; b0 < Bc; b0 += cb) {
        int cbc = (Bc - b0 < cb) ? (Bc - b0) : cb;
        int nTok = cbc * Lc;
        float* xrs = xres + (size_t)b0 * Lc * DIMc;

        for (int i = 0; i < 6; i++) {
            ln_k<<<nTok / 4, 256, 0, stream>>>(xrs, ln1_s + i * DIMc, ln1_b + i * DIMc, T4);
            gemm_mfma<384, 0, false, false><<<dim3(nTok / 128, 12), 256, 0, stream>>>(
                T4, in_w + (size_t)i * 2 * DINNERc * DIMc, nullptr, XZ, 1536, 1536);
            conv_k<<<nTok * DINNERc / 256, 256, 0, stream>>>(
                XZ, conv_w + (size_t)i * DINNERc * DCONVc, conv_b + (size_t)i * DINNERc,
                U, nTok * DINNERc);
            gemm_mfma<768, 0, false, false><<<dim3(nTok / 128, 1), 256, 0, stream>>>(
                U, xproj_w + (size_t)i * 56 * DINNERc, nullptr, DBL, 56, 56);
            dtproj_k<<<nTok * DINNERc / 256, 256, 0, stream>>>(
                DBL, dtproj_w + (size_t)i * DINNERc * DTRANKc, dtproj_b + (size_t)i * DINNERc,
                XZ, nTok * DINNERc);
            scan1_k<<<cbc * NCc * 3, 256, 0, stream>>>(
                XZ, U, DBL, A_log + (size_t)i * DINNERc * DSTATEc, SP, SH);
            scan2_k<<<(cbc * DINNERc * DSTATEc + 255) / 256, 256, 0, stream>>>(
                SP, SH, SH0, cbc * DINNERc * DSTATEc);
            scan3_k<<<cbc * NCc * 3, 256, 0, stream>>>(
                XZ, U, DBL, XZ, A_log + (size_t)i * DINNERc * DSTATEc,
                Dp + (size_t)i * DINNERc, SH0, U);
            gemm_mfma<768, 0, false, true><<<dim3(nTok / 128, 3), 256, 0, stream>>>(
                U, out_w + (size_t)i * DIMc * DINNERc, nullptr, xrs, 384, 384);
            ln_k<<<nTok / 4, 256, 0, stream>>>(xrs, ff_ln_s + i * DIMc, ff_ln_b + i * DIMc, T4);
            gemm_mfma<384, 1, true, false><<<dim3(nTok / 128, 6), 256, 0, stream>>>(
                T4, ff_w1 + (size_t)i * HIDc * DIMc, ff_b1 + (size_t)i * HIDc, XZ, 768, 768);
            gemm_mfma<768, 0, true, true><<<dim3(nTok / 128, 3), 256, 0, stream>>>(
                XZ, ff_w2 + (size_t)i * DIMc * HIDc, ff_b2 + (size_t)i * DIMc, xrs, 384, 384);
        }
        ln_k<<<nTok / 4, 256, 0, stream>>>(xrs, lno_s, lno_b, xrs);   // in-place final LN
    }
}